// Round 9
// baseline (287.440 us; speedup 1.0000x reference)
//
#include <hip/hip_runtime.h>
#include <hip/hip_bf16.h>
#include <stdint.h>

#define B_ 4
#define S_ 2048
#define D_ 1024
#define H_ 16
#define DH_ 64
#define BH_ 64
#define M_ 8192   // B_*S_

typedef __bf16 bf16;
typedef __attribute__((ext_vector_type(4))) __bf16 bf16x4;
typedef __attribute__((ext_vector_type(8))) __bf16 bf16x8;
typedef __attribute__((ext_vector_type(4))) float f32x4;
typedef __attribute__((ext_vector_type(8))) float f32x8;

#define EXP2F(x) __builtin_amdgcn_exp2f(x)

__device__ inline void gload16(const void* g, void* l) {
  __builtin_amdgcn_global_load_lds((const __attribute__((address_space(1))) void*)g,
                                   (__attribute__((address_space(3))) void*)l, 16, 0, 0);
}

// ---------------- 1. W (DxD fp32) -> W^T (bf16) ----------------
__global__ __launch_bounds__(256) void k_wt(const float* __restrict__ wq,
    const float* __restrict__ wk, const float* __restrict__ wv, bf16* __restrict__ o) {
  __shared__ float t[32][33];
  int z = blockIdx.z;
  const float* w = z == 0 ? wq : (z == 1 ? wk : wv);
  bf16* d = o + (size_t)z * D_ * D_;
  int bn = blockIdx.x * 32;  // col (n) of W
  int bk = blockIdx.y * 32;  // row (k) of W
  int tx = threadIdx.x & 31, ty = threadIdx.x >> 5;  // 32 x 8
#pragma unroll
  for (int j = 0; j < 32; j += 8) t[ty + j][tx] = w[(size_t)(bk + ty + j) * D_ + bn + tx];
  __syncthreads();
#pragma unroll
  for (int j = 0; j < 32; j += 8)
    d[(size_t)(bn + ty + j) * D_ + bk + tx] = (bf16)t[tx][ty + j];
}

// ---------------- 2. projection GEMM: X fp32 (8192x1024) @ W ----------------
// fp32->bf16 convert folded into A-staging, NOW PIPELINED (T14): A(k0+64)
// f32 loads issued right after the staging barrier so they fly under the
// MFMA phase and drain at the end-of-compute barrier. unroll 2 ping-pongs
// av/avn without copies. B via global_load_lds (L2-resident).
// z=0: Q [bh][s][64] (pre-scaled log2e/8); z=1: K; z=2: sigma-permuted V^T.
__global__ __launch_bounds__(256, 4) void k_proj(const float* __restrict__ Xq,
    const float* __restrict__ Xk, const float* __restrict__ Xv,
    const bf16* __restrict__ WT, bf16* __restrict__ Qo, bf16* __restrict__ Ko,
    bf16* __restrict__ VTo) {
  __shared__ bf16 lds[16384];  // A tile [128][64] elems [0,8192), B tile [8192,16384)
  int z = blockIdx.z;
  const float* Xz = z == 0 ? Xq : (z == 1 ? Xk : Xv);
  const char* Bb = (const char*)(WT + (size_t)z * D_ * D_);
  int m0 = blockIdx.x * 128, n0 = blockIdx.y * 128;
  int tid = threadIdx.x, lane = tid & 63, w = tid >> 6;
  int wr = w >> 1, wc = w & 1, fr = lane & 15, fg = lane >> 4;
  // A staging assignment: row = tid>>1 (0..127), k-half = (tid&1)*32
  int arow = tid >> 1, akr = (tid & 1) << 5;
  const float* asrc = Xz + (size_t)(m0 + arow) * D_ + akr;
  f32x4 acc[4][4];
#pragma unroll
  for (int a = 0; a < 4; a++)
#pragma unroll
    for (int b = 0; b < 4; b++) acc[a][b] = (f32x4){0.f, 0.f, 0.f, 0.f};

  f32x8 av[4], avn[4];
#pragma unroll
  for (int j = 0; j < 4; j++) av[j] = *(const f32x8*)(asrc + j * 8);

#pragma unroll 2
  for (int k0 = 0; k0 < D_; k0 += 64) {
    // B tile: 16 KB via global_load_lds (pre-swizzled source)
#pragma unroll
    for (int it = 0; it < 4; ++it) {
      int ow = 16384 + (w + 4 * it) * 1024;  // wave-uniform byte offset
      int lo = ow + lane * 16 - 16384;
      int row = lo >> 7;
      int db = (lo & 127) ^ ((row & 7) << 4);
      gload16(Bb + (size_t)(n0 + row) * 2048 + k0 * 2 + db, (char*)lds + ow);
    }
    // A tile: cvt current regs -> XOR-swizzled ds_write
#pragma unroll
    for (int j = 0; j < 4; j++) {
      bf16x8 ab;
#pragma unroll
      for (int e = 0; e < 8; e++) ab[e] = (bf16)av[j][e];
      int elem = (akr + j * 8) ^ ((arow & 7) << 3);
      *(bf16x8*)&lds[arow * 64 + elem] = ab;
    }
    __syncthreads();   // drains B gload_lds + A ds_writes
    // issue NEXT A-tile f32 loads: they fly under the MFMA phase below and
    // drain at the end-of-compute barrier (earliest legal issue slot).
    if (k0 + 64 < D_) {
#pragma unroll
      for (int j = 0; j < 4; j++) avn[j] = *(const f32x8*)(asrc + k0 + 64 + j * 8);
    }
#pragma unroll
    for (int c = 0; c < 2; c++) {
      bf16x8 af[4], bfr[4];
#pragma unroll
      for (int mi = 0; mi < 4; mi++) {
        int row = wr * 64 + mi * 16 + fr;
        af[mi] = *(const bf16x8*)&lds[row * 64 + ((fg * 8 + 32 * c) ^ ((row & 7) << 3))];
      }
#pragma unroll
      for (int ni = 0; ni < 4; ni++) {
        int row = wc * 64 + ni * 16 + fr;
        bfr[ni] = *(const bf16x8*)&lds[8192 + row * 64 + ((fg * 8 + 32 * c) ^ ((row & 7) << 3))];
      }
#pragma unroll
      for (int mi = 0; mi < 4; mi++)
#pragma unroll
        for (int ni = 0; ni < 4; ni++)
          acc[mi][ni] = __builtin_amdgcn_mfma_f32_16x16x32_bf16(af[mi], bfr[ni],
                                                                acc[mi][ni], 0, 0, 0);
    }
    __syncthreads();   // WAR for next ds_write; also drains avn loads
#pragma unroll
    for (int j = 0; j < 4; j++) av[j] = avn[j];
  }
  if (z == 2) {
    // V epilogue: VT[bh][d][blk*64 + slot], slot = sigma^-1(key); key low2 = r
#pragma unroll
    for (int mi = 0; mi < 4; mi++) {
      int row = m0 + wr * 64 + mi * 16 + 4 * fg;   // r = 0 base
      int bI = row >> 11, s = row & 2047;
      int blk = s >> 6, kk = s & 63;
      int slot = (kk & 0x23) | ((kk & 0x0C) << 1) | ((kk & 0x10) >> 2);
#pragma unroll
      for (int ni = 0; ni < 4; ni++) {
        int col = n0 + wc * 64 + ni * 16 + fr;
        int h = col >> 6, d = col & 63;
        bf16x4 vv = (bf16x4){(bf16)acc[mi][ni][0], (bf16)acc[mi][ni][1],
                             (bf16)acc[mi][ni][2], (bf16)acc[mi][ni][3]};
        *(bf16x4*)&VTo[((size_t)(bI * H_ + h) * DH_ + d) * S_ + blk * 64 + slot] = vv;
      }
    }
  } else {
    bf16* O = z == 0 ? Qo : Ko;
    // Q: fold 1/sqrt(dh) AND log2(e) so softmax can use exp2 directly.
    float sc = (z == 0) ? 0.18033688011112042f : 1.0f;
#pragma unroll
    for (int mi = 0; mi < 4; mi++)
#pragma unroll
      for (int r = 0; r < 4; r++) {
        int row = m0 + wr * 64 + mi * 16 + 4 * fg + r;
        int b = row >> 11, s = row & 2047;
#pragma unroll
        for (int ni = 0; ni < 4; ni++) {
          int col = n0 + wc * 64 + ni * 16 + fr;
          int h = col >> 6, d = col & 63;
          O[((size_t)(b * H_ + h) * S_ + s) * DH_ + d] = (bf16)(acc[mi][ni][r] * sc);
        }
      }
  }
}

// ---------------- 3. flash attention ----------------
// 8 waves x 16 q-rows (block = 128 q). KBLK=64, double-buffered K/V staging
// (2-phase: barrier -> STAGE(t+1, buf^1) -> compute(buf)), staging GUARDED.
// kt unrolled x2 -> compile-time buffer offsets. Defer-max online softmax
// (THR=7); l via ones-MFMA; max tree via v_max3 fusion.
__global__ __launch_bounds__(512, 8) void k_attn(const bf16* __restrict__ Q,
    const bf16* __restrict__ Kt, const bf16* __restrict__ VT, float* __restrict__ out) {
  __shared__ bf16 kv[16384];    // 32KB: buf0 [0,8192) K | [8192] V ; buf1 at +8192 elems
  int g = blockIdx.x;
  int wg = (g & 7) * 128 + (g >> 3);   // 1024 % 8 == 0 -> bijective
  int qt = wg & 15, bh = wg >> 4;
  int b = bh >> 4, h = bh & 15;
  int tid = threadIdx.x, lane = tid & 63, w = tid >> 6;
  int fr = lane & 15, fg = lane >> 4;
  const char* Kb = (const char*)(Kt + (size_t)bh * S_ * DH_);
  const char* Vb = (const char*)(VT + (size_t)bh * DH_ * S_);
  int q0 = qt * 128 + w * 16;

  // per-thread staging sources (512 thr x 16B = 8KB per region per round)
  int o0 = tid * 16;                       // byte offset within region [0,8192)
  int r0 = o0 >> 7, b0 = (o0 & 127) ^ ((r0 & 7) << 4);
  const char* kp = Kb + r0 * 128 + b0;     // +8192 B/tile
  const char* vp = Vb + r0 * 4096 + b0;    // +128 B/tile
  char* lb = (char*)kv;
  int w1024 = w * 1024;                    // wave-uniform LDS dest base

  bf16x8 qf[2];
#pragma unroll
  for (int c = 0; c < 2; c++)
    qf[c] = *(const bf16x8*)(Q + ((size_t)bh * S_ + q0 + fr) * DH_ + fg * 8 + 32 * c);
  float m_ = -1e30f;
  f32x4 o_[4];
#pragma unroll
  for (int ds = 0; ds < 4; ds++) o_[ds] = (f32x4){0.f, 0.f, 0.f, 0.f};
  f32x4 ol = (f32x4){0.f, 0.f, 0.f, 0.f};
  bf16x8 vones;
#pragma unroll
  for (int j = 0; j < 8; j++) vones[j] = (bf16)1.0f;

  // prologue: stage tile 0 into buf0
  gload16(kp, lb + w1024);
  gload16(vp, lb + 8192 + w1024);
  kp += 8192; vp += 128;

#pragma unroll 2
  for (int kt = 0; kt < 32; ++kt) {
    __syncthreads();            // drains STAGE(kt); prior reads of buf^1 done
    if (kt + 1 < 32) {          // stage next tile; lands during compute below
      const int nb = ((kt + 1) & 1) << 14;
      gload16(kp, lb + nb + w1024);
      gload16(vp, lb + nb + 8192 + w1024);
      kp += 8192; vp += 128;
    }
    const int cb = (kt & 1) << 13;   // compile-time under unroll 2
    // swapped QK^T: st[ks] = D[key][q], col=q=fr, key = 16ks + 4fg + r
    f32x4 st[4];
    __builtin_amdgcn_s_setprio(1);
#pragma unroll
    for (int ks = 0; ks < 4; ks++) {
      int row = ks * 16 + fr;
      bf16x8 kf0 = *(const bf16x8*)&kv[cb + row * 64 + ((fg * 8) ^ ((row & 7) << 3))];
      bf16x8 kf1 = *(const bf16x8*)&kv[cb + row * 64 + ((fg * 8 + 32) ^ ((row & 7) << 3))];
      f32x4 a = (f32x4){0.f, 0.f, 0.f, 0.f};
      a = __builtin_amdgcn_mfma_f32_16x16x32_bf16(kf0, qf[0], a, 0, 0, 0);
      a = __builtin_amdgcn_mfma_f32_16x16x32_bf16(kf1, qf[1], a, 0, 0, 0);
      st[ks] = a;
    }
    __builtin_amdgcn_s_setprio(0);
    // online softmax with defer-max (T13): keep p <= 2^7 (round-4-validated)
    // max tree as fmaxf triples -> v_max3_f32 fusion (T17)
    float ma = fmaxf(fmaxf(st[0][0], st[0][1]), st[0][2]);
    float mb = fmaxf(fmaxf(st[0][3], st[1][0]), st[1][1]);
    float mc = fmaxf(fmaxf(st[1][2], st[1][3]), st[2][0]);
    float md = fmaxf(fmaxf(st[2][1], st[2][2]), st[2][3]);
    float me = fmaxf(fmaxf(st[3][0], st[3][1]), st[3][2]);
    float mx = fmaxf(fmaxf(fmaxf(ma, mb), mc), fmaxf(fmaxf(md, me), st[3][3]));
    mx = fmaxf(mx, __shfl_xor(mx, 16));
    mx = fmaxf(mx, __shfl_xor(mx, 32));
    if (!__all(mx - m_ <= 7.0f)) {
      float mnew = fmaxf(m_, mx);
      float sf = EXP2F(m_ - mnew);
      m_ = mnew;
      float s0 = __shfl(sf, 4 * fg + 0);
      float s1 = __shfl(sf, 4 * fg + 1);
      float s2 = __shfl(sf, 4 * fg + 2);
      float s3 = __shfl(sf, 4 * fg + 3);
#pragma unroll
      for (int ds = 0; ds < 4; ds++) {
        o_[ds][0] *= s0; o_[ds][1] *= s1;
        o_[ds][2] *= s2; o_[ds][3] *= s3;
      }
      ol[0] *= s0; ol[1] *= s1; ol[2] *= s2; ol[3] *= s3;
    }
#pragma unroll
    for (int ks = 0; ks < 4; ks++)
#pragma unroll
      for (int r = 0; r < 4; r++) st[ks][r] = EXP2F(st[ks][r] - m_);
    bf16x8 pa[2];
    pa[0] = (bf16x8){(bf16)st[0][0], (bf16)st[0][1], (bf16)st[0][2], (bf16)st[0][3],
                     (bf16)st[1][0], (bf16)st[1][1], (bf16)st[1][2], (bf16)st[1][3]};
    pa[1] = (bf16x8){(bf16)st[2][0], (bf16)st[2][1], (bf16)st[2][2], (bf16)st[2][3],
                     (bf16)st[3][0], (bf16)st[3][1], (bf16)st[3][2], (bf16)st[3][3]};
    // PV + row-sum(l) via ones-MFMA
    __builtin_amdgcn_s_setprio(1);
    ol = __builtin_amdgcn_mfma_f32_16x16x32_bf16(pa[0], vones, ol, 0, 0, 0);
    ol = __builtin_amdgcn_mfma_f32_16x16x32_bf16(pa[1], vones, ol, 0, 0, 0);
#pragma unroll
    for (int c = 0; c < 2; c++) {
#pragma unroll
      for (int ds = 0; ds < 4; ds++) {
        int row = ds * 16 + fr;
        bf16x8 vf = *(const bf16x8*)&kv[cb + 4096 + row * 64 + ((fg * 8 + 32 * c) ^ ((row & 7) << 3))];
        o_[ds] = __builtin_amdgcn_mfma_f32_16x16x32_bf16(pa[c], vf, o_[ds], 0, 0, 0);
      }
    }
    __builtin_amdgcn_s_setprio(0);
  }
  // finalize: ol[r] = l[q=4fg+r] (replicated over fr) -> no shuffles
#pragma unroll
  for (int r = 0; r < 4; r++) {
    float inv = 1.0f / ol[r];
    int s = q0 + 4 * fg + r;
#pragma unroll
    for (int ds = 0; ds < 4; ds++) {
      int col = h * DH_ + ds * 16 + fr;
      out[((size_t)b * S_ + s) * D_ + col] = o_[ds][r] * inv;
    }
  }
}

extern "C" void kernel_launch(void* const* d_in, const int* in_sizes, int n_in,
                              void* d_out, int out_size, void* d_ws, size_t ws_size,
                              hipStream_t stream) {
  (void)in_sizes; (void)n_in; (void)out_size; (void)ws_size;
  const float* q  = (const float*)d_in[0];
  const float* k  = (const float*)d_in[1];
  const float* v  = (const float*)d_in[2];
  const float* wq = (const float*)d_in[3];
  const float* wk = (const float*)d_in[4];
  const float* wv = (const float*)d_in[5];
  float* out = (float*)d_out;
  char* ws = (char*)d_ws;
  size_t off = 0;
  bf16* wt = (bf16*)(ws + off); off += (size_t)3 * D_ * D_ * 2;    //  6.3 MB
  bf16* Qw = (bf16*)(ws + off); off += (size_t)BH_ * S_ * DH_ * 2; // 16.8 MB
  bf16* Kw = (bf16*)(ws + off); off += (size_t)BH_ * S_ * DH_ * 2;
  bf16* Vt = (bf16*)(ws + off); off += (size_t)BH_ * S_ * DH_ * 2;

  k_wt  <<<dim3(32, 32, 3), 256, 0, stream>>>(wq, wk, wv, wt);
  k_proj<<<dim3(64, 8, 3), 256, 0, stream>>>(q, k, v, wt, Qw, Kw, Vt);
  k_attn<<<dim3(1024), 512, 0, stream>>>(Qw, Kw, Vt, out);
}

// Round 10
// 184.888 us; speedup vs baseline: 1.5547x; 1.5547x over previous
//
#include <hip/hip_runtime.h>
#include <hip/hip_bf16.h>
#include <stdint.h>

#define B_ 4
#define S_ 2048
#define D_ 1024
#define H_ 16
#define DH_ 64
#define BH_ 64
#define M_ 8192   // B_*S_

typedef __bf16 bf16;
typedef __attribute__((ext_vector_type(4))) __bf16 bf16x4;
typedef __attribute__((ext_vector_type(8))) __bf16 bf16x8;
typedef __attribute__((ext_vector_type(4))) float f32x4;
typedef __attribute__((ext_vector_type(8))) float f32x8;

#define EXP2F(x) __builtin_amdgcn_exp2f(x)

__device__ inline void gload16(const void* g, void* l) {
  __builtin_amdgcn_global_load_lds((const __attribute__((address_space(1))) void*)g,
                                   (__attribute__((address_space(3))) void*)l, 16, 0, 0);
}

// ---------------- 1. fp32 -> bf16 convert of q/k/v (split kernel: the fused
// variants were latency-bound (r8) or spilled (r9); this is pure-BW ~25us) ----
__global__ __launch_bounds__(256) void k_conv(const float* __restrict__ q,
    const float* __restrict__ k, const float* __restrict__ v, bf16* __restrict__ o) {
  int z = blockIdx.y;
  const float* s = z == 0 ? q : (z == 1 ? k : v);
  bf16* d = o + (size_t)z * ((size_t)M_ * D_);
  int n8 = M_ * D_ / 8;
  for (int i = blockIdx.x * 256 + threadIdx.x; i < n8; i += gridDim.x * 256) {
    f32x8 f = ((const f32x8*)s)[i];
    bf16x8 b;
#pragma unroll
    for (int j = 0; j < 8; j++) b[j] = (bf16)f[j];
    ((bf16x8*)d)[i] = b;
  }
}

// ---------------- 2. W (DxD fp32) -> W^T (bf16) ----------------
__global__ __launch_bounds__(256) void k_wt(const float* __restrict__ wq,
    const float* __restrict__ wk, const float* __restrict__ wv, bf16* __restrict__ o) {
  __shared__ float t[32][33];
  int z = blockIdx.z;
  const float* w = z == 0 ? wq : (z == 1 ? wk : wv);
  bf16* d = o + (size_t)z * D_ * D_;
  int bn = blockIdx.x * 32;  // col (n) of W
  int bk = blockIdx.y * 32;  // row (k) of W
  int tx = threadIdx.x & 31, ty = threadIdx.x >> 5;  // 32 x 8
#pragma unroll
  for (int j = 0; j < 32; j += 8) t[ty + j][tx] = w[(size_t)(bk + ty + j) * D_ + bn + tx];
  __syncthreads();
#pragma unroll
  for (int j = 0; j < 32; j += 8)
    d[(size_t)(bn + ty + j) * D_ + bk + tx] = (bf16)t[tx][ty + j];
}

// ---------------- 3. projection GEMM: X(8192x1024) @ W -> per-head layout ----
// Both A and B staged via global_load_lds (pre-swizzled source). r6-validated.
// z=0: Q [bh][s][64] (pre-scaled log2e/8); z=1: K; z=2: sigma-permuted V^T.
__global__ __launch_bounds__(256) void k_proj(const bf16* __restrict__ X,
    const bf16* __restrict__ WT, bf16* __restrict__ Qo, bf16* __restrict__ Ko,
    bf16* __restrict__ VTo) {
  __shared__ bf16 lds[16384];  // A tile [128][64] elems [0,8192), B tile [8192,16384)
  int z = blockIdx.z;
  const char* Ab = (const char*)(X + (size_t)z * M_ * D_);
  const char* Bb = (const char*)(WT + (size_t)z * D_ * D_);
  int m0 = blockIdx.x * 128, n0 = blockIdx.y * 128;
  int tid = threadIdx.x, lane = tid & 63, w = tid >> 6;
  int wr = w >> 1, wc = w & 1, fr = lane & 15, fg = lane >> 4;
  f32x4 acc[4][4];
#pragma unroll
  for (int a = 0; a < 4; a++)
#pragma unroll
    for (int b = 0; b < 4; b++) acc[a][b] = (f32x4){0.f, 0.f, 0.f, 0.f};

  for (int k0 = 0; k0 < D_; k0 += 64) {
#pragma unroll
    for (int it = 0; it < 8; ++it) {
      int ow = (w + 4 * it) * 1024;   // wave-uniform LDS byte offset
      int o = ow + lane * 16;         // this lane's byte slot
      const char* src;
      if (o < 16384) {                // A region
        int row = o >> 7;
        int db = (o & 127) ^ ((row & 7) << 4);
        src = Ab + (size_t)(m0 + row) * 2048 + k0 * 2 + db;
      } else {                        // B region
        int lo = o - 16384, row = lo >> 7;
        int db = (lo & 127) ^ ((row & 7) << 4);
        src = Bb + (size_t)(n0 + row) * 2048 + k0 * 2 + db;
      }
      gload16(src, (char*)lds + ow);
    }
    __syncthreads();
#pragma unroll
    for (int c = 0; c < 2; c++) {
      bf16x8 af[4], bfr[4];
#pragma unroll
      for (int mi = 0; mi < 4; mi++) {
        int row = wr * 64 + mi * 16 + fr;
        af[mi] = *(const bf16x8*)&lds[row * 64 + ((fg * 8 + 32 * c) ^ ((row & 7) << 3))];
      }
#pragma unroll
      for (int ni = 0; ni < 4; ni++) {
        int row = wc * 64 + ni * 16 + fr;
        bfr[ni] = *(const bf16x8*)&lds[8192 + row * 64 + ((fg * 8 + 32 * c) ^ ((row & 7) << 3))];
      }
#pragma unroll
      for (int mi = 0; mi < 4; mi++)
#pragma unroll
        for (int ni = 0; ni < 4; ni++)
          acc[mi][ni] = __builtin_amdgcn_mfma_f32_16x16x32_bf16(af[mi], bfr[ni],
                                                                acc[mi][ni], 0, 0, 0);
    }
    __syncthreads();
  }
  if (z == 2) {
    // V epilogue: VT[bh][d][blk*64 + slot], slot = sigma^-1(key); key low2 = r
    // -> 4 consecutive slots -> one 8B store per fragment.
#pragma unroll
    for (int mi = 0; mi < 4; mi++) {
      int row = m0 + wr * 64 + mi * 16 + 4 * fg;   // r = 0 base
      int bI = row >> 11, s = row & 2047;
      int blk = s >> 6, kk = s & 63;
      int slot = (kk & 0x23) | ((kk & 0x0C) << 1) | ((kk & 0x10) >> 2);
#pragma unroll
      for (int ni = 0; ni < 4; ni++) {
        int col = n0 + wc * 64 + ni * 16 + fr;
        int h = col >> 6, d = col & 63;
        bf16x4 vv = (bf16x4){(bf16)acc[mi][ni][0], (bf16)acc[mi][ni][1],
                             (bf16)acc[mi][ni][2], (bf16)acc[mi][ni][3]};
        *(bf16x4*)&VTo[((size_t)(bI * H_ + h) * DH_ + d) * S_ + blk * 64 + slot] = vv;
      }
    }
  } else {
    bf16* O = z == 0 ? Qo : Ko;
    // Q: fold 1/sqrt(dh) AND log2(e) so softmax can use exp2 directly.
    float sc = (z == 0) ? 0.18033688011112042f : 1.0f;
#pragma unroll
    for (int mi = 0; mi < 4; mi++)
#pragma unroll
      for (int r = 0; r < 4; r++) {
        int row = m0 + wr * 64 + mi * 16 + 4 * fg + r;
        int b = row >> 11, s = row & 2047;
#pragma unroll
        for (int ni = 0; ni < 4; ni++) {
          int col = n0 + wc * 64 + ni * 16 + fr;
          int h = col >> 6, d = col & 63;
          O[((size_t)(b * H_ + h) * S_ + s) * DH_ + d] = (bf16)(acc[mi][ni][r] * sc);
        }
      }
  }
}

// ---------------- 4. flash attention ----------------
// 8 waves x 16 q-rows (block = 128 q). KBLK=64, double-buffered K/V staging
// (2-phase: barrier -> STAGE(t+1, buf^1) -> compute(buf)), staging GUARDED.
// kt unrolled x2 -> compile-time buffer offsets. Defer-max online softmax
// (THR=7); l via ones-MFMA; max tree via v_max3 fusion.
__global__ __launch_bounds__(512, 8) void k_attn(const bf16* __restrict__ Q,
    const bf16* __restrict__ Kt, const bf16* __restrict__ VT, float* __restrict__ out) {
  __shared__ bf16 kv[16384];    // 32KB: buf0 [0,8192) K | [8192] V ; buf1 at +8192 elems
  int g = blockIdx.x;
  int wg = (g & 7) * 128 + (g >> 3);   // 1024 % 8 == 0 -> bijective
  int qt = wg & 15, bh = wg >> 4;
  int b = bh >> 4, h = bh & 15;
  int tid = threadIdx.x, lane = tid & 63, w = tid >> 6;
  int fr = lane & 15, fg = lane >> 4;
  const char* Kb = (const char*)(Kt + (size_t)bh * S_ * DH_);
  const char* Vb = (const char*)(VT + (size_t)bh * DH_ * S_);
  int q0 = qt * 128 + w * 16;

  // per-thread staging sources (512 thr x 16B = 8KB per region per round)
  int o0 = tid * 16;                       // byte offset within region [0,8192)
  int r0 = o0 >> 7, b0 = (o0 & 127) ^ ((r0 & 7) << 4);
  const char* kp = Kb + r0 * 128 + b0;     // +8192 B/tile
  const char* vp = Vb + r0 * 4096 + b0;    // +128 B/tile
  char* lb = (char*)kv;
  int w1024 = w * 1024;                    // wave-uniform LDS dest base

  bf16x8 qf[2];
#pragma unroll
  for (int c = 0; c < 2; c++)
    qf[c] = *(const bf16x8*)(Q + ((size_t)bh * S_ + q0 + fr) * DH_ + fg * 8 + 32 * c);
  float m_ = -1e30f;
  f32x4 o_[4];
#pragma unroll
  for (int ds = 0; ds < 4; ds++) o_[ds] = (f32x4){0.f, 0.f, 0.f, 0.f};
  f32x4 ol = (f32x4){0.f, 0.f, 0.f, 0.f};
  bf16x8 vones;
#pragma unroll
  for (int j = 0; j < 8; j++) vones[j] = (bf16)1.0f;

  // prologue: stage tile 0 into buf0
  gload16(kp, lb + w1024);
  gload16(vp, lb + 8192 + w1024);
  kp += 8192; vp += 128;

#pragma unroll 2
  for (int kt = 0; kt < 32; ++kt) {
    __syncthreads();            // drains STAGE(kt); prior reads of buf^1 done
    if (kt + 1 < 32) {          // stage next tile; lands during compute below
      const int nb = ((kt + 1) & 1) << 14;
      gload16(kp, lb + nb + w1024);
      gload16(vp, lb + nb + 8192 + w1024);
      kp += 8192; vp += 128;
    }
    const int cb = (kt & 1) << 13;   // compile-time under unroll 2
    // swapped QK^T: st[ks] = D[key][q], col=q=fr, key = 16ks + 4fg + r
    f32x4 st[4];
    __builtin_amdgcn_s_setprio(1);
#pragma unroll
    for (int ks = 0; ks < 4; ks++) {
      int row = ks * 16 + fr;
      bf16x8 kf0 = *(const bf16x8*)&kv[cb + row * 64 + ((fg * 8) ^ ((row & 7) << 3))];
      bf16x8 kf1 = *(const bf16x8*)&kv[cb + row * 64 + ((fg * 8 + 32) ^ ((row & 7) << 3))];
      f32x4 a = (f32x4){0.f, 0.f, 0.f, 0.f};
      a = __builtin_amdgcn_mfma_f32_16x16x32_bf16(kf0, qf[0], a, 0, 0, 0);
      a = __builtin_amdgcn_mfma_f32_16x16x32_bf16(kf1, qf[1], a, 0, 0, 0);
      st[ks] = a;
    }
    __builtin_amdgcn_s_setprio(0);
    // online softmax with defer-max (T13): keep p <= 2^7 (round-4-validated)
    // max tree as fmaxf triples -> v_max3_f32 fusion (T17)
    float ma = fmaxf(fmaxf(st[0][0], st[0][1]), st[0][2]);
    float mb = fmaxf(fmaxf(st[0][3], st[1][0]), st[1][1]);
    float mc = fmaxf(fmaxf(st[1][2], st[1][3]), st[2][0]);
    float md = fmaxf(fmaxf(st[2][1], st[2][2]), st[2][3]);
    float me = fmaxf(fmaxf(st[3][0], st[3][1]), st[3][2]);
    float mx = fmaxf(fmaxf(fmaxf(ma, mb), mc), fmaxf(fmaxf(md, me), st[3][3]));
    mx = fmaxf(mx, __shfl_xor(mx, 16));
    mx = fmaxf(mx, __shfl_xor(mx, 32));
    if (!__all(mx - m_ <= 7.0f)) {
      float mnew = fmaxf(m_, mx);
      float sf = EXP2F(m_ - mnew);
      m_ = mnew;
      float s0 = __shfl(sf, 4 * fg + 0);
      float s1 = __shfl(sf, 4 * fg + 1);
      float s2 = __shfl(sf, 4 * fg + 2);
      float s3 = __shfl(sf, 4 * fg + 3);
#pragma unroll
      for (int ds = 0; ds < 4; ds++) {
        o_[ds][0] *= s0; o_[ds][1] *= s1;
        o_[ds][2] *= s2; o_[ds][3] *= s3;
      }
      ol[0] *= s0; ol[1] *= s1; ol[2] *= s2; ol[3] *= s3;
    }
#pragma unroll
    for (int ks = 0; ks < 4; ks++)
#pragma unroll
      for (int r = 0; r < 4; r++) st[ks][r] = EXP2F(st[ks][r] - m_);
    bf16x8 pa[2];
    pa[0] = (bf16x8){(bf16)st[0][0], (bf16)st[0][1], (bf16)st[0][2], (bf16)st[0][3],
                     (bf16)st[1][0], (bf16)st[1][1], (bf16)st[1][2], (bf16)st[1][3]};
    pa[1] = (bf16x8){(bf16)st[2][0], (bf16)st[2][1], (bf16)st[2][2], (bf16)st[2][3],
                     (bf16)st[3][0], (bf16)st[3][1], (bf16)st[3][2], (bf16)st[3][3]};
    // PV + row-sum(l) via ones-MFMA
    __builtin_amdgcn_s_setprio(1);
    ol = __builtin_amdgcn_mfma_f32_16x16x32_bf16(pa[0], vones, ol, 0, 0, 0);
    ol = __builtin_amdgcn_mfma_f32_16x16x32_bf16(pa[1], vones, ol, 0, 0, 0);
#pragma unroll
    for (int c = 0; c < 2; c++) {
#pragma unroll
      for (int ds = 0; ds < 4; ds++) {
        int row = ds * 16 + fr;
        bf16x8 vf = *(const bf16x8*)&kv[cb + 4096 + row * 64 + ((fg * 8 + 32 * c) ^ ((row & 7) << 3))];
        o_[ds] = __builtin_amdgcn_mfma_f32_16x16x32_bf16(pa[c], vf, o_[ds], 0, 0, 0);
      }
    }
    __builtin_amdgcn_s_setprio(0);
  }
  // finalize: ol[r] = l[q=4fg+r] (replicated over fr) -> no shuffles
#pragma unroll
  for (int r = 0; r < 4; r++) {
    float inv = 1.0f / ol[r];
    int s = q0 + 4 * fg + r;
#pragma unroll
    for (int ds = 0; ds < 4; ds++) {
      int col = h * DH_ + ds * 16 + fr;
      out[((size_t)b * S_ + s) * D_ + col] = o_[ds][r] * inv;
    }
  }
}

extern "C" void kernel_launch(void* const* d_in, const int* in_sizes, int n_in,
                              void* d_out, int out_size, void* d_ws, size_t ws_size,
                              hipStream_t stream) {
  (void)in_sizes; (void)n_in; (void)out_size; (void)ws_size;
  const float* q  = (const float*)d_in[0];
  const float* k  = (const float*)d_in[1];
  const float* v  = (const float*)d_in[2];
  const float* wq = (const float*)d_in[3];
  const float* wk = (const float*)d_in[4];
  const float* wv = (const float*)d_in[5];
  float* out = (float*)d_out;
  char* ws = (char*)d_ws;
  size_t off = 0;
  bf16* xb = (bf16*)(ws + off); off += (size_t)3 * M_ * D_ * 2;    // 50.3 MB
  bf16* wt = (bf16*)(ws + off); off += (size_t)3 * D_ * D_ * 2;    //  6.3 MB
  bf16* Qw = (bf16*)(ws + off); off += (size_t)BH_ * S_ * DH_ * 2; // 16.8 MB
  bf16* Kw = (bf16*)(ws + off); off += (size_t)BH_ * S_ * DH_ * 2;
  bf16* Vt = (bf16*)(ws + off); off += (size_t)BH_ * S_ * DH_ * 2;

  k_conv<<<dim3(1024, 3), 256, 0, stream>>>(q, k, v, xb);
  k_wt  <<<dim3(32, 32, 3), 256, 0, stream>>>(wq, wk, wv, wt);
  k_proj<<<dim3(64, 8, 3), 256, 0, stream>>>(xb, wt, Qw, Kw, Vt);
  k_attn<<<dim3(1024), 512, 0, stream>>>(Qw, Kw, Vt, out);
}

// Round 11
// 184.829 us; speedup vs baseline: 1.5552x; 1.0003x over previous
//
#include <hip/hip_runtime.h>
#include <hip/hip_bf16.h>
#include <stdint.h>

#define B_ 4
#define S_ 2048
#define D_ 1024
#define H_ 16
#define DH_ 64
#define BH_ 64
#define M_ 8192   // B_*S_

typedef __bf16 bf16;
typedef __attribute__((ext_vector_type(4))) __bf16 bf16x4;
typedef __attribute__((ext_vector_type(8))) __bf16 bf16x8;
typedef __attribute__((ext_vector_type(4))) float f32x4;
typedef __attribute__((ext_vector_type(8))) float f32x8;

#define EXP2F(x) __builtin_amdgcn_exp2f(x)

__device__ inline void gload16(const void* g, void* l) {
  __builtin_amdgcn_global_load_lds((const __attribute__((address_space(1))) void*)g,
                                   (__attribute__((address_space(3))) void*)l, 16, 0, 0);
}

// ---------------- 1. fp32 -> bf16 convert of q/k/v (split kernel: the fused
// variants were latency-bound (r8) or spilled (r9); this is pure-BW ~25us) ----
__global__ __launch_bounds__(256) void k_conv(const float* __restrict__ q,
    const float* __restrict__ k, const float* __restrict__ v, bf16* __restrict__ o) {
  int z = blockIdx.y;
  const float* s = z == 0 ? q : (z == 1 ? k : v);
  bf16* d = o + (size_t)z * ((size_t)M_ * D_);
  int n8 = M_ * D_ / 8;
  for (int i = blockIdx.x * 256 + threadIdx.x; i < n8; i += gridDim.x * 256) {
    f32x8 f = ((const f32x8*)s)[i];
    bf16x8 b;
#pragma unroll
    for (int j = 0; j < 8; j++) b[j] = (bf16)f[j];
    ((bf16x8*)d)[i] = b;
  }
}

// ---------------- 2. W (DxD fp32) -> W^T (bf16) ----------------
__global__ __launch_bounds__(256) void k_wt(const float* __restrict__ wq,
    const float* __restrict__ wk, const float* __restrict__ wv, bf16* __restrict__ o) {
  __shared__ float t[32][33];
  int z = blockIdx.z;
  const float* w = z == 0 ? wq : (z == 1 ? wk : wv);
  bf16* d = o + (size_t)z * D_ * D_;
  int bn = blockIdx.x * 32;  // col (n) of W
  int bk = blockIdx.y * 32;  // row (k) of W
  int tx = threadIdx.x & 31, ty = threadIdx.x >> 5;  // 32 x 8
#pragma unroll
  for (int j = 0; j < 32; j += 8) t[ty + j][tx] = w[(size_t)(bk + ty + j) * D_ + bn + tx];
  __syncthreads();
#pragma unroll
  for (int j = 0; j < 32; j += 8)
    d[(size_t)(bn + ty + j) * D_ + bk + tx] = (bf16)t[tx][ty + j];
}

// ---------------- 3. projection GEMM: X(8192x1024) @ W -> per-head layout ----
// Both A and B staged via global_load_lds (pre-swizzled source). r6-validated.
// z=0: Q [bh][s][64] (pre-scaled log2e/8); z=1: K; z=2: sigma-permuted V^T.
__global__ __launch_bounds__(256) void k_proj(const bf16* __restrict__ X,
    const bf16* __restrict__ WT, bf16* __restrict__ Qo, bf16* __restrict__ Ko,
    bf16* __restrict__ VTo) {
  __shared__ bf16 lds[16384];  // A tile [128][64] elems [0,8192), B tile [8192,16384)
  int z = blockIdx.z;
  const char* Ab = (const char*)(X + (size_t)z * M_ * D_);
  const char* Bb = (const char*)(WT + (size_t)z * D_ * D_);
  int m0 = blockIdx.x * 128, n0 = blockIdx.y * 128;
  int tid = threadIdx.x, lane = tid & 63, w = tid >> 6;
  int wr = w >> 1, wc = w & 1, fr = lane & 15, fg = lane >> 4;
  f32x4 acc[4][4];
#pragma unroll
  for (int a = 0; a < 4; a++)
#pragma unroll
    for (int b = 0; b < 4; b++) acc[a][b] = (f32x4){0.f, 0.f, 0.f, 0.f};

  for (int k0 = 0; k0 < D_; k0 += 64) {
#pragma unroll
    for (int it = 0; it < 8; ++it) {
      int ow = (w + 4 * it) * 1024;   // wave-uniform LDS byte offset
      int o = ow + lane * 16;         // this lane's byte slot
      const char* src;
      if (o < 16384) {                // A region
        int row = o >> 7;
        int db = (o & 127) ^ ((row & 7) << 4);
        src = Ab + (size_t)(m0 + row) * 2048 + k0 * 2 + db;
      } else {                        // B region
        int lo = o - 16384, row = lo >> 7;
        int db = (lo & 127) ^ ((row & 7) << 4);
        src = Bb + (size_t)(n0 + row) * 2048 + k0 * 2 + db;
      }
      gload16(src, (char*)lds + ow);
    }
    __syncthreads();
#pragma unroll
    for (int c = 0; c < 2; c++) {
      bf16x8 af[4], bfr[4];
#pragma unroll
      for (int mi = 0; mi < 4; mi++) {
        int row = wr * 64 + mi * 16 + fr;
        af[mi] = *(const bf16x8*)&lds[row * 64 + ((fg * 8 + 32 * c) ^ ((row & 7) << 3))];
      }
#pragma unroll
      for (int ni = 0; ni < 4; ni++) {
        int row = wc * 64 + ni * 16 + fr;
        bfr[ni] = *(const bf16x8*)&lds[8192 + row * 64 + ((fg * 8 + 32 * c) ^ ((row & 7) << 3))];
      }
#pragma unroll
      for (int mi = 0; mi < 4; mi++)
#pragma unroll
        for (int ni = 0; ni < 4; ni++)
          acc[mi][ni] = __builtin_amdgcn_mfma_f32_16x16x32_bf16(af[mi], bfr[ni],
                                                                acc[mi][ni], 0, 0, 0);
    }
    __syncthreads();
  }
  if (z == 2) {
    // V epilogue: VT[bh][d][blk*64 + slot], slot = sigma^-1(key); key low2 = r
    // -> 4 consecutive slots -> one 8B store per fragment.
#pragma unroll
    for (int mi = 0; mi < 4; mi++) {
      int row = m0 + wr * 64 + mi * 16 + 4 * fg;   // r = 0 base
      int bI = row >> 11, s = row & 2047;
      int blk = s >> 6, kk = s & 63;
      int slot = (kk & 0x23) | ((kk & 0x0C) << 1) | ((kk & 0x10) >> 2);
#pragma unroll
      for (int ni = 0; ni < 4; ni++) {
        int col = n0 + wc * 64 + ni * 16 + fr;
        int h = col >> 6, d = col & 63;
        bf16x4 vv = (bf16x4){(bf16)acc[mi][ni][0], (bf16)acc[mi][ni][1],
                             (bf16)acc[mi][ni][2], (bf16)acc[mi][ni][3]};
        *(bf16x4*)&VTo[((size_t)(bI * H_ + h) * DH_ + d) * S_ + blk * 64 + slot] = vv;
      }
    }
  } else {
    bf16* O = z == 0 ? Qo : Ko;
    // Q: fold 1/sqrt(dh) AND log2(e) so softmax can use exp2 directly.
    float sc = (z == 0) ? 0.18033688011112042f : 1.0f;
#pragma unroll
    for (int mi = 0; mi < 4; mi++)
#pragma unroll
      for (int r = 0; r < 4; r++) {
        int row = m0 + wr * 64 + mi * 16 + 4 * fg + r;
        int b = row >> 11, s = row & 2047;
#pragma unroll
        for (int ni = 0; ni < 4; ni++) {
          int col = n0 + wc * 64 + ni * 16 + fr;
          int h = col >> 6, d = col & 63;
          O[((size_t)(b * H_ + h) * S_ + s) * DH_ + d] = (bf16)(acc[mi][ni][r] * sc);
        }
      }
  }
}

// ---------------- 4. flash attention ----------------
// 8 waves x 16 q-rows (block = 128 q). KBLK=64, double-buffered K/V staging
// (2-phase: barrier -> STAGE(t+1, buf^1) -> compute(buf)), staging GUARDED.
// kt unrolled x2 -> compile-time buffer offsets. ADDRESS-HOISTED ds_reads:
// swizzle XOR term is lane-invariant across ks/ds (row&7 == fr&7), so all 16
// inner reads = 4 persistent base pointers + compile-time offsets (folds into
// the 16-bit ds_read offset: immediate). Defer-max softmax (THR=7); l via
// ones-MFMA; max tree via v_max3 fusion.
__global__ __launch_bounds__(512, 8) void k_attn(const bf16* __restrict__ Q,
    const bf16* __restrict__ Kt, const bf16* __restrict__ VT, float* __restrict__ out) {
  __shared__ bf16 kv[16384];    // 32KB: buf0 [0,8192) K | [8192] V ; buf1 at +8192 elems
  int g = blockIdx.x;
  int wg = (g & 7) * 128 + (g >> 3);   // 1024 % 8 == 0 -> bijective
  int qt = wg & 15, bh = wg >> 4;
  int b = bh >> 4, h = bh & 15;
  int tid = threadIdx.x, lane = tid & 63, w = tid >> 6;
  int fr = lane & 15, fg = lane >> 4;
  const char* Kb = (const char*)(Kt + (size_t)bh * S_ * DH_);
  const char* Vb = (const char*)(VT + (size_t)bh * DH_ * S_);
  int q0 = qt * 128 + w * 16;

  // per-thread staging sources (512 thr x 16B = 8KB per region per round)
  int o0 = tid * 16;                       // byte offset within region [0,8192)
  int r0 = o0 >> 7, b0 = (o0 & 127) ^ ((r0 & 7) << 4);
  const char* kp = Kb + r0 * 128 + b0;     // +8192 B/tile
  const char* vp = Vb + r0 * 4096 + b0;    // +128 B/tile
  char* lb = (char*)kv;
  int w1024 = w * 1024;                    // wave-uniform LDS dest base

  // hoisted LDS read bases: row = {ks,ds}*16 + fr -> row&7 == fr&7 loop-inv.
  const int swz = (fr & 7) << 3;
  const bf16* kb0 = &kv[fr * 64 + ((fg * 8) ^ swz)];
  const bf16* kb1 = &kv[fr * 64 + ((fg * 8 + 32) ^ swz)];
  const bf16* vb0 = kb0 + 4096;
  const bf16* vb1 = kb1 + 4096;

  bf16x8 qf[2];
#pragma unroll
  for (int c = 0; c < 2; c++)
    qf[c] = *(const bf16x8*)(Q + ((size_t)bh * S_ + q0 + fr) * DH_ + fg * 8 + 32 * c);
  float m_ = -1e30f;
  f32x4 o_[4];
#pragma unroll
  for (int ds = 0; ds < 4; ds++) o_[ds] = (f32x4){0.f, 0.f, 0.f, 0.f};
  f32x4 ol = (f32x4){0.f, 0.f, 0.f, 0.f};
  bf16x8 vones;
#pragma unroll
  for (int j = 0; j < 8; j++) vones[j] = (bf16)1.0f;

  // prologue: stage tile 0 into buf0
  gload16(kp, lb + w1024);
  gload16(vp, lb + 8192 + w1024);
  kp += 8192; vp += 128;

#pragma unroll 2
  for (int kt = 0; kt < 32; ++kt) {
    __syncthreads();            // drains STAGE(kt); prior reads of buf^1 done
    if (kt + 1 < 32) {          // stage next tile; lands during compute below
      const int nb = ((kt + 1) & 1) << 14;
      gload16(kp, lb + nb + w1024);
      gload16(vp, lb + nb + 8192 + w1024);
      kp += 8192; vp += 128;
    }
    const int cb = (kt & 1) << 13;   // elems; compile-time under unroll 2
    // swapped QK^T: st[ks] = D[key][q], col=q=fr, key = 16ks + 4fg + r
    f32x4 st[4];
    __builtin_amdgcn_s_setprio(1);
#pragma unroll
    for (int ks = 0; ks < 4; ks++) {
      bf16x8 kf0 = *(const bf16x8*)(kb0 + cb + ks * 1024);
      bf16x8 kf1 = *(const bf16x8*)(kb1 + cb + ks * 1024);
      f32x4 a = (f32x4){0.f, 0.f, 0.f, 0.f};
      a = __builtin_amdgcn_mfma_f32_16x16x32_bf16(kf0, qf[0], a, 0, 0, 0);
      a = __builtin_amdgcn_mfma_f32_16x16x32_bf16(kf1, qf[1], a, 0, 0, 0);
      st[ks] = a;
    }
    __builtin_amdgcn_s_setprio(0);
    // online softmax with defer-max (T13): keep p <= 2^7 (round-4-validated)
    // max tree as fmaxf triples -> v_max3_f32 fusion (T17)
    float ma = fmaxf(fmaxf(st[0][0], st[0][1]), st[0][2]);
    float mb = fmaxf(fmaxf(st[0][3], st[1][0]), st[1][1]);
    float mc = fmaxf(fmaxf(st[1][2], st[1][3]), st[2][0]);
    float md = fmaxf(fmaxf(st[2][1], st[2][2]), st[2][3]);
    float me = fmaxf(fmaxf(st[3][0], st[3][1]), st[3][2]);
    float mx = fmaxf(fmaxf(fmaxf(ma, mb), mc), fmaxf(fmaxf(md, me), st[3][3]));
    mx = fmaxf(mx, __shfl_xor(mx, 16));
    mx = fmaxf(mx, __shfl_xor(mx, 32));
    if (!__all(mx - m_ <= 7.0f)) {
      float mnew = fmaxf(m_, mx);
      float sf = EXP2F(m_ - mnew);
      m_ = mnew;
      float s0 = __shfl(sf, 4 * fg + 0);
      float s1 = __shfl(sf, 4 * fg + 1);
      float s2 = __shfl(sf, 4 * fg + 2);
      float s3 = __shfl(sf, 4 * fg + 3);
#pragma unroll
      for (int ds = 0; ds < 4; ds++) {
        o_[ds][0] *= s0; o_[ds][1] *= s1;
        o_[ds][2] *= s2; o_[ds][3] *= s3;
      }
      ol[0] *= s0; ol[1] *= s1; ol[2] *= s2; ol[3] *= s3;
    }
#pragma unroll
    for (int ks = 0; ks < 4; ks++)
#pragma unroll
      for (int r = 0; r < 4; r++) st[ks][r] = EXP2F(st[ks][r] - m_);
    bf16x8 pa[2];
    pa[0] = (bf16x8){(bf16)st[0][0], (bf16)st[0][1], (bf16)st[0][2], (bf16)st[0][3],
                     (bf16)st[1][0], (bf16)st[1][1], (bf16)st[1][2], (bf16)st[1][3]};
    pa[1] = (bf16x8){(bf16)st[2][0], (bf16)st[2][1], (bf16)st[2][2], (bf16)st[2][3],
                     (bf16)st[3][0], (bf16)st[3][1], (bf16)st[3][2], (bf16)st[3][3]};
    // PV + row-sum(l) via ones-MFMA
    __builtin_amdgcn_s_setprio(1);
    ol = __builtin_amdgcn_mfma_f32_16x16x32_bf16(pa[0], vones, ol, 0, 0, 0);
    ol = __builtin_amdgcn_mfma_f32_16x16x32_bf16(pa[1], vones, ol, 0, 0, 0);
#pragma unroll
    for (int c = 0; c < 2; c++) {
      const bf16* vbc = c ? vb1 : vb0;
#pragma unroll
      for (int ds = 0; ds < 4; ds++) {
        bf16x8 vf = *(const bf16x8*)(vbc + cb + ds * 1024);
        o_[ds] = __builtin_amdgcn_mfma_f32_16x16x32_bf16(pa[c], vf, o_[ds], 0, 0, 0);
      }
    }
    __builtin_amdgcn_s_setprio(0);
  }
  // finalize: ol[r] = l[q=4fg+r] (replicated over fr) -> no shuffles
#pragma unroll
  for (int r = 0; r < 4; r++) {
    float inv = 1.0f / ol[r];
    int s = q0 + 4 * fg + r;
#pragma unroll
    for (int ds = 0; ds < 4; ds++) {
      int col = h * DH_ + ds * 16 + fr;
      out[((size_t)b * S_ + s) * D_ + col] = o_[ds][r] * inv;
    }
  }
}

extern "C" void kernel_launch(void* const* d_in, const int* in_sizes, int n_in,
                              void* d_out, int out_size, void* d_ws, size_t ws_size,
                              hipStream_t stream) {
  (void)in_sizes; (void)n_in; (void)out_size; (void)ws_size;
  const float* q  = (const float*)d_in[0];
  const float* k  = (const float*)d_in[1];
  const float* v  = (const float*)d_in[2];
  const float* wq = (const float*)d_in[3];
  const float* wk = (const float*)d_in[4];
  const float* wv = (const float*)d_in[5];
  float* out = (float*)d_out;
  char* ws = (char*)d_ws;
  size_t off = 0;
  bf16* xb = (bf16*)(ws + off); off += (size_t)3 * M_ * D_ * 2;    // 50.3 MB
  bf16* wt = (bf16*)(ws + off); off += (size_t)3 * D_ * D_ * 2;    //  6.3 MB
  bf16* Qw = (bf16*)(ws + off); off += (size_t)BH_ * S_ * DH_ * 2; // 16.8 MB
  bf16* Kw = (bf16*)(ws + off); off += (size_t)BH_ * S_ * DH_ * 2;
  bf16* Vt = (bf16*)(ws + off); off += (size_t)BH_ * S_ * DH_ * 2;

  k_conv<<<dim3(1024, 3), 256, 0, stream>>>(q, k, v, xb);
  k_wt  <<<dim3(32, 32, 3), 256, 0, stream>>>(wq, wk, wv, wt);
  k_proj<<<dim3(64, 8, 3), 256, 0, stream>>>(xb, wt, Qw, Kw, Vt);
  k_attn<<<dim3(1024), 512, 0, stream>>>(Qw, Kw, Vt, out);
}

// Round 12
// 171.302 us; speedup vs baseline: 1.6780x; 1.0790x over previous
//
#include <hip/hip_runtime.h>
#include <hip/hip_bf16.h>
#include <stdint.h>

#define B_ 4
#define S_ 2048
#define D_ 1024
#define H_ 16
#define DH_ 64
#define BH_ 64
#define M_ 8192   // B_*S_

typedef __bf16 bf16;
typedef __attribute__((ext_vector_type(4))) __bf16 bf16x4;
typedef __attribute__((ext_vector_type(8))) __bf16 bf16x8;
typedef __attribute__((ext_vector_type(4))) float f32x4;
typedef __attribute__((ext_vector_type(8))) float f32x8;

#define EXP2F(x) __builtin_amdgcn_exp2f(x)

__device__ inline void gload16(const void* g, void* l) {
  __builtin_amdgcn_global_load_lds((const __attribute__((address_space(1))) void*)g,
                                   (__attribute__((address_space(3))) void*)l, 16, 0, 0);
}

// ---------------- 1. fp32 -> bf16 convert of q/k/v (split kernel: the fused
// variants were latency-bound (r8) or spilled (r9); this is pure-BW ~25us) ----
__global__ __launch_bounds__(256) void k_conv(const float* __restrict__ q,
    const float* __restrict__ k, const float* __restrict__ v, bf16* __restrict__ o) {
  int z = blockIdx.y;
  const float* s = z == 0 ? q : (z == 1 ? k : v);
  bf16* d = o + (size_t)z * ((size_t)M_ * D_);
  int n8 = M_ * D_ / 8;
  for (int i = blockIdx.x * 256 + threadIdx.x; i < n8; i += gridDim.x * 256) {
    f32x8 f = ((const f32x8*)s)[i];
    bf16x8 b;
#pragma unroll
    for (int j = 0; j < 8; j++) b[j] = (bf16)f[j];
    ((bf16x8*)d)[i] = b;
  }
}

// ---------------- 2. W (DxD fp32) -> W^T (bf16) ----------------
__global__ __launch_bounds__(256) void k_wt(const float* __restrict__ wq,
    const float* __restrict__ wk, const float* __restrict__ wv, bf16* __restrict__ o) {
  __shared__ float t[32][33];
  int z = blockIdx.z;
  const float* w = z == 0 ? wq : (z == 1 ? wk : wv);
  bf16* d = o + (size_t)z * D_ * D_;
  int bn = blockIdx.x * 32;  // col (n) of W
  int bk = blockIdx.y * 32;  // row (k) of W
  int tx = threadIdx.x & 31, ty = threadIdx.x >> 5;  // 32 x 8
#pragma unroll
  for (int j = 0; j < 32; j += 8) t[ty + j][tx] = w[(size_t)(bk + ty + j) * D_ + bn + tx];
  __syncthreads();
#pragma unroll
  for (int j = 0; j < 32; j += 8)
    d[(size_t)(bn + ty + j) * D_ + bk + tx] = (bf16)t[tx][ty + j];
}

// ---------------- 3. projection GEMM: X(8192x1024) @ W -> per-head layout ----
// Both A and B staged via global_load_lds (pre-swizzled source). r6-validated.
// z=0: Q [bh][s][64] (pre-scaled log2e/8); z=1: K; z=2: sigma-permuted V^T.
__global__ __launch_bounds__(256) void k_proj(const bf16* __restrict__ X,
    const bf16* __restrict__ WT, bf16* __restrict__ Qo, bf16* __restrict__ Ko,
    bf16* __restrict__ VTo) {
  __shared__ bf16 lds[16384];  // A tile [128][64] elems [0,8192), B tile [8192,16384)
  int z = blockIdx.z;
  const char* Ab = (const char*)(X + (size_t)z * M_ * D_);
  const char* Bb = (const char*)(WT + (size_t)z * D_ * D_);
  int m0 = blockIdx.x * 128, n0 = blockIdx.y * 128;
  int tid = threadIdx.x, lane = tid & 63, w = tid >> 6;
  int wr = w >> 1, wc = w & 1, fr = lane & 15, fg = lane >> 4;
  f32x4 acc[4][4];
#pragma unroll
  for (int a = 0; a < 4; a++)
#pragma unroll
    for (int b = 0; b < 4; b++) acc[a][b] = (f32x4){0.f, 0.f, 0.f, 0.f};

  for (int k0 = 0; k0 < D_; k0 += 64) {
#pragma unroll
    for (int it = 0; it < 8; ++it) {
      int ow = (w + 4 * it) * 1024;   // wave-uniform LDS byte offset
      int o = ow + lane * 16;         // this lane's byte slot
      const char* src;
      if (o < 16384) {                // A region
        int row = o >> 7;
        int db = (o & 127) ^ ((row & 7) << 4);
        src = Ab + (size_t)(m0 + row) * 2048 + k0 * 2 + db;
      } else {                        // B region
        int lo = o - 16384, row = lo >> 7;
        int db = (lo & 127) ^ ((row & 7) << 4);
        src = Bb + (size_t)(n0 + row) * 2048 + k0 * 2 + db;
      }
      gload16(src, (char*)lds + ow);
    }
    __syncthreads();
#pragma unroll
    for (int c = 0; c < 2; c++) {
      bf16x8 af[4], bfr[4];
#pragma unroll
      for (int mi = 0; mi < 4; mi++) {
        int row = wr * 64 + mi * 16 + fr;
        af[mi] = *(const bf16x8*)&lds[row * 64 + ((fg * 8 + 32 * c) ^ ((row & 7) << 3))];
      }
#pragma unroll
      for (int ni = 0; ni < 4; ni++) {
        int row = wc * 64 + ni * 16 + fr;
        bfr[ni] = *(const bf16x8*)&lds[8192 + row * 64 + ((fg * 8 + 32 * c) ^ ((row & 7) << 3))];
      }
#pragma unroll
      for (int mi = 0; mi < 4; mi++)
#pragma unroll
        for (int ni = 0; ni < 4; ni++)
          acc[mi][ni] = __builtin_amdgcn_mfma_f32_16x16x32_bf16(af[mi], bfr[ni],
                                                                acc[mi][ni], 0, 0, 0);
    }
    __syncthreads();
  }
  if (z == 2) {
    // V epilogue: VT[bh][d][blk*64 + slot], slot = sigma^-1(key); key low2 = r
    // -> 4 consecutive slots -> one 8B store per fragment.
#pragma unroll
    for (int mi = 0; mi < 4; mi++) {
      int row = m0 + wr * 64 + mi * 16 + 4 * fg;   // r = 0 base
      int bI = row >> 11, s = row & 2047;
      int blk = s >> 6, kk = s & 63;
      int slot = (kk & 0x23) | ((kk & 0x0C) << 1) | ((kk & 0x10) >> 2);
#pragma unroll
      for (int ni = 0; ni < 4; ni++) {
        int col = n0 + wc * 64 + ni * 16 + fr;
        int h = col >> 6, d = col & 63;
        bf16x4 vv = (bf16x4){(bf16)acc[mi][ni][0], (bf16)acc[mi][ni][1],
                             (bf16)acc[mi][ni][2], (bf16)acc[mi][ni][3]};
        *(bf16x4*)&VTo[((size_t)(bI * H_ + h) * DH_ + d) * S_ + blk * 64 + slot] = vv;
      }
    }
  } else {
    bf16* O = z == 0 ? Qo : Ko;
    // Q: fold 1/sqrt(dh) AND log2(e) so softmax can use exp2 directly.
    float sc = (z == 0) ? 0.18033688011112042f : 1.0f;
#pragma unroll
    for (int mi = 0; mi < 4; mi++)
#pragma unroll
      for (int r = 0; r < 4; r++) {
        int row = m0 + wr * 64 + mi * 16 + 4 * fg + r;
        int b = row >> 11, s = row & 2047;
#pragma unroll
        for (int ni = 0; ni < 4; ni++) {
          int col = n0 + wc * 64 + ni * 16 + fr;
          int h = col >> 6, d = col & 63;
          O[((size_t)(b * H_ + h) * S_ + s) * DH_ + d] = (bf16)(acc[mi][ni][r] * sc);
        }
      }
  }
}

// ---------------- 4. flash attention ----------------
// 8 waves x 32 q-rows (block = 256 q, grid 512): doubling q/wave HALVES the
// dominant per-CU LDS-read traffic (4GB -> 2GB total) since each K/V fragment
// read now serves 2x the output. V fragments shared across both mi sub-tiles.
// KBLK=64, guarded dbuf staging, unroll-2 static offsets, defer-max (THR=7)
// per mi, l via ones-MFMA, v_max3 tree. XCD-swizzled (512 % 8 == 0).
__global__ __launch_bounds__(512, 4) void k_attn(const bf16* __restrict__ Q,
    const bf16* __restrict__ Kt, const bf16* __restrict__ VT, float* __restrict__ out) {
  __shared__ bf16 kv[16384];    // 32KB: buf0 [0,8192) K | [8192] V ; buf1 at +8192 elems
  int g = blockIdx.x;
  int wg = (g & 7) * 64 + (g >> 3);    // 512 % 8 == 0 -> bijective
  int qt = wg & 7, bh = wg >> 3;
  int b = bh >> 4, h = bh & 15;
  int tid = threadIdx.x, lane = tid & 63, w = tid >> 6;
  int fr = lane & 15, fg = lane >> 4;
  const char* Kb = (const char*)(Kt + (size_t)bh * S_ * DH_);
  const char* Vb = (const char*)(VT + (size_t)bh * DH_ * S_);
  int q0 = qt * 256 + w * 32;

  // per-thread staging sources (512 thr x 16B = 8KB per region per round)
  int o0 = tid * 16;                       // byte offset within region [0,8192)
  int r0 = o0 >> 7, b0 = (o0 & 127) ^ ((r0 & 7) << 4);
  const char* kp = Kb + r0 * 128 + b0;     // +8192 B/tile
  const char* vp = Vb + r0 * 4096 + b0;    // +128 B/tile
  char* lb = (char*)kv;
  int w1024 = w * 1024;                    // wave-uniform LDS dest base

  // hoisted LDS read bases: row = {ks,ds}*16 + fr -> row&7 == fr&7 loop-inv.
  const int swz = (fr & 7) << 3;
  const bf16* kb0 = &kv[fr * 64 + ((fg * 8) ^ swz)];
  const bf16* kb1 = &kv[fr * 64 + ((fg * 8 + 32) ^ swz)];
  const bf16* vb0 = kb0 + 4096;
  const bf16* vb1 = kb1 + 4096;

  bf16x8 qf[2][2];
#pragma unroll
  for (int mi = 0; mi < 2; mi++)
#pragma unroll
    for (int c = 0; c < 2; c++)
      qf[mi][c] = *(const bf16x8*)(Q + ((size_t)bh * S_ + q0 + mi * 16 + fr) * DH_ + fg * 8 + 32 * c);
  float m_[2] = {-1e30f, -1e30f};
  f32x4 o_[2][4];
#pragma unroll
  for (int mi = 0; mi < 2; mi++)
#pragma unroll
    for (int ds = 0; ds < 4; ds++) o_[mi][ds] = (f32x4){0.f, 0.f, 0.f, 0.f};
  f32x4 ol[2] = {(f32x4){0.f, 0.f, 0.f, 0.f}, (f32x4){0.f, 0.f, 0.f, 0.f}};
  bf16x8 vones;
#pragma unroll
  for (int j = 0; j < 8; j++) vones[j] = (bf16)1.0f;

  // prologue: stage tile 0 into buf0
  gload16(kp, lb + w1024);
  gload16(vp, lb + 8192 + w1024);
  kp += 8192; vp += 128;

#pragma unroll 2
  for (int kt = 0; kt < 32; ++kt) {
    __syncthreads();            // drains STAGE(kt); prior reads of buf^1 done
    if (kt + 1 < 32) {          // stage next tile; lands during compute below
      const int nb = ((kt + 1) & 1) << 14;
      gload16(kp, lb + nb + w1024);
      gload16(vp, lb + nb + 8192 + w1024);
      kp += 8192; vp += 128;
    }
    const int cb = (kt & 1) << 13;   // elems; compile-time under unroll 2
    // swapped QK^T: st[mi][ks] = D[key][q], col=q=fr, key = 16ks + 4fg + r
    f32x4 st[2][4];
    __builtin_amdgcn_s_setprio(1);
#pragma unroll
    for (int ks = 0; ks < 4; ks++) {
      bf16x8 kf0 = *(const bf16x8*)(kb0 + cb + ks * 1024);
      bf16x8 kf1 = *(const bf16x8*)(kb1 + cb + ks * 1024);
#pragma unroll
      for (int mi = 0; mi < 2; mi++) {
        f32x4 a = (f32x4){0.f, 0.f, 0.f, 0.f};
        a = __builtin_amdgcn_mfma_f32_16x16x32_bf16(kf0, qf[mi][0], a, 0, 0, 0);
        a = __builtin_amdgcn_mfma_f32_16x16x32_bf16(kf1, qf[mi][1], a, 0, 0, 0);
        st[mi][ks] = a;
      }
    }
    __builtin_amdgcn_s_setprio(0);
    // per-mi online softmax with defer-max (T13), v_max3 tree (T17)
    bf16x8 pa[2][2];
#pragma unroll
    for (int mi = 0; mi < 2; mi++) {
      float ma = fmaxf(fmaxf(st[mi][0][0], st[mi][0][1]), st[mi][0][2]);
      float mb = fmaxf(fmaxf(st[mi][0][3], st[mi][1][0]), st[mi][1][1]);
      float mc = fmaxf(fmaxf(st[mi][1][2], st[mi][1][3]), st[mi][2][0]);
      float md = fmaxf(fmaxf(st[mi][2][1], st[mi][2][2]), st[mi][2][3]);
      float me = fmaxf(fmaxf(st[mi][3][0], st[mi][3][1]), st[mi][3][2]);
      float mx = fmaxf(fmaxf(fmaxf(ma, mb), mc), fmaxf(fmaxf(md, me), st[mi][3][3]));
      mx = fmaxf(mx, __shfl_xor(mx, 16));
      mx = fmaxf(mx, __shfl_xor(mx, 32));
      if (!__all(mx - m_[mi] <= 7.0f)) {
        float mnew = fmaxf(m_[mi], mx);
        float sf = EXP2F(m_[mi] - mnew);
        m_[mi] = mnew;
        float s0 = __shfl(sf, 4 * fg + 0);
        float s1 = __shfl(sf, 4 * fg + 1);
        float s2 = __shfl(sf, 4 * fg + 2);
        float s3 = __shfl(sf, 4 * fg + 3);
#pragma unroll
        for (int ds = 0; ds < 4; ds++) {
          o_[mi][ds][0] *= s0; o_[mi][ds][1] *= s1;
          o_[mi][ds][2] *= s2; o_[mi][ds][3] *= s3;
        }
        ol[mi][0] *= s0; ol[mi][1] *= s1; ol[mi][2] *= s2; ol[mi][3] *= s3;
      }
#pragma unroll
      for (int ks = 0; ks < 4; ks++)
#pragma unroll
        for (int r = 0; r < 4; r++) st[mi][ks][r] = EXP2F(st[mi][ks][r] - m_[mi]);
      pa[mi][0] = (bf16x8){(bf16)st[mi][0][0], (bf16)st[mi][0][1], (bf16)st[mi][0][2],
                           (bf16)st[mi][0][3], (bf16)st[mi][1][0], (bf16)st[mi][1][1],
                           (bf16)st[mi][1][2], (bf16)st[mi][1][3]};
      pa[mi][1] = (bf16x8){(bf16)st[mi][2][0], (bf16)st[mi][2][1], (bf16)st[mi][2][2],
                           (bf16)st[mi][2][3], (bf16)st[mi][3][0], (bf16)st[mi][3][1],
                           (bf16)st[mi][3][2], (bf16)st[mi][3][3]};
    }
    // PV + row-sum(l) via ones-MFMA; V fragments SHARED across both mi
    __builtin_amdgcn_s_setprio(1);
#pragma unroll
    for (int mi = 0; mi < 2; mi++) {
      ol[mi] = __builtin_amdgcn_mfma_f32_16x16x32_bf16(pa[mi][0], vones, ol[mi], 0, 0, 0);
      ol[mi] = __builtin_amdgcn_mfma_f32_16x16x32_bf16(pa[mi][1], vones, ol[mi], 0, 0, 0);
    }
#pragma unroll
    for (int c = 0; c < 2; c++) {
      const bf16* vbc = c ? vb1 : vb0;
#pragma unroll
      for (int ds = 0; ds < 4; ds++) {
        bf16x8 vf = *(const bf16x8*)(vbc + cb + ds * 1024);
        o_[0][ds] = __builtin_amdgcn_mfma_f32_16x16x32_bf16(pa[0][c], vf, o_[0][ds], 0, 0, 0);
        o_[1][ds] = __builtin_amdgcn_mfma_f32_16x16x32_bf16(pa[1][c], vf, o_[1][ds], 0, 0, 0);
      }
    }
    __builtin_amdgcn_s_setprio(0);
  }
  // finalize: ol[mi][r] = l[q = q0+mi*16+4fg+r] (replicated over fr)
#pragma unroll
  for (int mi = 0; mi < 2; mi++)
#pragma unroll
    for (int r = 0; r < 4; r++) {
      float inv = 1.0f / ol[mi][r];
      int s = q0 + mi * 16 + 4 * fg + r;
#pragma unroll
      for (int ds = 0; ds < 4; ds++) {
        int col = h * DH_ + ds * 16 + fr;
        out[((size_t)b * S_ + s) * D_ + col] = o_[mi][ds][r] * inv;
      }
    }
}

extern "C" void kernel_launch(void* const* d_in, const int* in_sizes, int n_in,
                              void* d_out, int out_size, void* d_ws, size_t ws_size,
                              hipStream_t stream) {
  (void)in_sizes; (void)n_in; (void)out_size; (void)ws_size;
  const float* q  = (const float*)d_in[0];
  const float* k  = (const float*)d_in[1];
  const float* v  = (const float*)d_in[2];
  const float* wq = (const float*)d_in[3];
  const float* wk = (const float*)d_in[4];
  const float* wv = (const float*)d_in[5];
  float* out = (float*)d_out;
  char* ws = (char*)d_ws;
  size_t off = 0;
  bf16* xb = (bf16*)(ws + off); off += (size_t)3 * M_ * D_ * 2;    // 50.3 MB
  bf16* wt = (bf16*)(ws + off); off += (size_t)3 * D_ * D_ * 2;    //  6.3 MB
  bf16* Qw = (bf16*)(ws + off); off += (size_t)BH_ * S_ * DH_ * 2; // 16.8 MB
  bf16* Kw = (bf16*)(ws + off); off += (size_t)BH_ * S_ * DH_ * 2;
  bf16* Vt = (bf16*)(ws + off); off += (size_t)BH_ * S_ * DH_ * 2;

  k_conv<<<dim3(1024, 3), 256, 0, stream>>>(q, k, v, xb);
  k_wt  <<<dim3(32, 32, 3), 256, 0, stream>>>(wq, wk, wv, wt);
  k_proj<<<dim3(64, 8, 3), 256, 0, stream>>>(xb, wt, Qw, Kw, Vt);
  k_attn<<<dim3(512), 512, 0, stream>>>(Qw, Kw, Vt, out);
}